// Round 9
// baseline (105.144 us; speedup 1.0000x reference)
//
#include <hip/hip_runtime.h>
#include <math.h>

#define NB 4096
#define ND 512
#define K2 1024
#define NT8 8  // K2 / 128 K-tiles

typedef __attribute__((ext_vector_type(4))) float f32x4;
typedef __attribute__((ext_vector_type(16))) float f32x16;
typedef __attribute__((ext_vector_type(8))) int i32x8;

__device__ __forceinline__ float wave_sum(float v) {
#pragma unroll
  for (int o = 32; o > 0; o >>= 1) v += __shfl_xor(v, o);
  return v;
}

// ---------------------------------------------------------------------------
// Kernel 1: build A=[v_mean|v_sigma], B=[t_mean|t_sigma] in fp8 e4m3
// (4096x1024, 1 B/elem), plus exact f32 row square-norms
// a_sq[i] = Σ mean² + Σ var (σ²=var). Blocks 0..4095 A-side, 4096..8191 B.
// ---------------------------------------------------------------------------
__global__ __launch_bounds__(256) void prep_kernel(
    const float* __restrict__ v_mean, const float* __restrict__ v_var,
    const float* __restrict__ t_mean, const float* __restrict__ t_var,
    unsigned char* __restrict__ Afp, unsigned char* __restrict__ Bfp,
    float* __restrict__ a_sq, float* __restrict__ b_sq) {
  int b = blockIdx.x;
  int side = b >> 12;
  int row = b & (NB - 1);
  const float* mean = side ? t_mean : v_mean;
  const float* var = side ? t_var : v_var;
  unsigned char* dst = side ? Bfp : Afp;
  float* sq = side ? b_sq : a_sq;
  int t = threadIdx.x;
  float2 m2 = *(const float2*)(mean + (size_t)row * ND + 2 * t);
  float2 v2 = *(const float2*)(var + (size_t)row * ND + 2 * t);
  float s0 = sqrtf(v2.x), s1 = sqrtf(v2.y);
  int pm = __builtin_amdgcn_cvt_pk_fp8_f32(m2.x, m2.y, 0, false);
  int ps = __builtin_amdgcn_cvt_pk_fp8_f32(s0, s1, 0, false);
  *(unsigned short*)(dst + (size_t)row * K2 + 2 * t) = (unsigned short)(pm & 0xFFFF);
  *(unsigned short*)(dst + (size_t)row * K2 + ND + 2 * t) = (unsigned short)(ps & 0xFFFF);
  float p = m2.x * m2.x + m2.y * m2.y + v2.x + v2.y;
  p = wave_sum(p);
  __shared__ float sm[4];
  if ((t & 63) == 0) sm[t >> 6] = p;
  __syncthreads();
  if (t == 0) sq[row] = (sm[0] + sm[1]) + (sm[2] + sm[3]);
}

// ---------------------------------------------------------------------------
// Kernel 2: 128x256-tile fp8 GEMM via mfma_scale_f32_32x32x64_f8f6f4 with
// unit scales (E8M0 127 = x1.0). BK=128, DOUBLE-buffered LDS (96 KiB),
// 8 waves (2Mx4N, wave = 64x64 = 2x2 of 32x32). __launch_bounds__(512,2).
//
// R8 lesson: the scheduler hoisted BOTH k-steps' fragment loads (64 VGPR)
// above the first MFMA cluster -> peak arch liveness > 128 -> 120 MB of
// scratch traffic. Fix: sched_barrier(0) fences between
// {k0-loads | k0-MFMA | k1-loads | k1-MFMA} cap concurrent frags at 32.
//
// LDS swizzle 32B-granular: phys_byte = logical ^ ((row&3)<<5); operands stay
// contiguous (direct i32x8 load). Staged with inverse-swizzled global source
// (rule #21). Residual 8-way read conflict costs ~12% (measured R8) — accepted.
// Fused online-LSE partials in the epilogue:
//   rowM/rowS[row][64]  ch = bn*4+wc    colM/colS[col][64]  ch = bm*2+wr
// ---------------------------------------------------------------------------
__global__ __launch_bounds__(512, 2) void gemm_fused_kernel(
    const unsigned char* __restrict__ Afp, const unsigned char* __restrict__ Bfp,
    const float* __restrict__ a_sq, const float* __restrict__ b_sq,
    const float* __restrict__ log_temp,
    float* __restrict__ rowM, float* __restrict__ rowS,
    float* __restrict__ colM, float* __restrict__ colS,
    float* __restrict__ diag) {
  __shared__ unsigned char ldsA[2][128 * 128];  // 2 x 16 KB
  __shared__ unsigned char ldsB[2][256 * 128];  // 2 x 32 KB
  int bid = blockIdx.x;
  // XCD-aware swizzle: 512 blocks, 8 XCDs -> 64 contiguous per XCD (bijective).
  int swz = (bid & 7) * 64 + (bid >> 3);
  int bm = swz >> 4, bn = swz & 15;  // 32 x 16 grid
  int brow = bm * 128, bcol = bn * 256;
  int tid = threadIdx.x;
  int lane = tid & 63, wid = tid >> 6;
  int wr = wid >> 2, wc = wid & 3;  // 2x4 wave grid, wave = 64x64
  int l31 = lane & 31, kh = lane >> 5;

  // Precomputed staging offsets (6 loads/thread): global byte offsets with
  // inverse swizzle, and linear LDS byte offsets.
  int rbase = tid >> 3, chunk = tid & 7;
  unsigned gA[2], gB[4];
  int ldA[2], ldB[4];
#pragma unroll
  for (int s = 0; s < 2; ++s) {
    int row = s * 64 + rbase;
    gA[s] = (unsigned)(brow + row) * K2 + ((chunk * 16) ^ ((row & 3) << 5));
    ldA[s] = row * 128 + chunk * 16;
  }
#pragma unroll
  for (int s = 0; s < 4; ++s) {
    int row = s * 64 + rbase;
    gB[s] = (unsigned)(bcol + row) * K2 + ((chunk * 16) ^ ((row & 3) << 5));
    ldB[s] = row * 128 + chunk * 16;
  }

#define STAGE(T, C)                                                            \
  {                                                                            \
    _Pragma("unroll") for (int s = 0; s < 2; ++s)                              \
        __builtin_amdgcn_global_load_lds(                                      \
            (const __attribute__((address_space(1))) unsigned int*)(Afp +      \
                gA[s] + (unsigned)(T) * 128),                                  \
            (__attribute__((address_space(3))) unsigned int*)(&ldsA[C][0] +    \
                ldA[s]),                                                       \
            16, 0, 0);                                                         \
    _Pragma("unroll") for (int s = 0; s < 4; ++s)                              \
        __builtin_amdgcn_global_load_lds(                                      \
            (const __attribute__((address_space(1))) unsigned int*)(Bfp +      \
                gB[s] + (unsigned)(T) * 128),                                  \
            (__attribute__((address_space(3))) unsigned int*)(&ldsB[C][0] +    \
                ldB[s]),                                                       \
            16, 0, 0);                                                         \
  }

  // Per-lane fragment byte offsets. MFMA 32x32 A/B layout: row = lane&31,
  // k = (lane>>5)*32 + j (32 contiguous). k-step 1 address = k-step 0 ^ 64
  // (valid under the 32B swizzle since XOR is associative).
  unsigned sws = (unsigned)(lane & 3) << 5;
  unsigned aOff[2], bOff[2];
#pragma unroll
  for (int mi = 0; mi < 2; ++mi)
    aOff[mi] = (unsigned)(wr * 64 + mi * 32 + l31) * 128 + (((unsigned)kh * 32) ^ sws);
#pragma unroll
  for (int ni = 0; ni < 2; ++ni)
    bOff[ni] = (unsigned)(wc * 64 + ni * 32 + l31) * 128 + (((unsigned)kh * 32) ^ sws);

  f32x16 acc[2][2] = {};

  STAGE(0, 0);
  asm volatile("s_waitcnt vmcnt(0)" ::: "memory");
  __builtin_amdgcn_s_barrier();

  for (int t = 0; t < NT8; ++t) {
    const int c = t & 1;
    const unsigned char* bufa = &ldsA[c][0];
    const unsigned char* bufb = &ldsB[c][0];
    // Issue next tile's stage into the OTHER buffer first (latency hides
    // under this tile's ds_read + MFMA).
    if (t + 1 < NT8) STAGE(t + 1, c ^ 1);
    // ---- cluster 1: k-step 0 fragment loads (32 VGPR) ----
    i32x8 fa0 = *(const i32x8*)(bufa + aOff[0]);
    i32x8 fa1 = *(const i32x8*)(bufa + aOff[1]);
    i32x8 fb0 = *(const i32x8*)(bufb + bOff[0]);
    i32x8 fb1 = *(const i32x8*)(bufb + bOff[1]);
    __builtin_amdgcn_sched_barrier(0);
    // ---- cluster 2: k-step 0 MFMA ----
    __builtin_amdgcn_s_setprio(1);
    acc[0][0] = __builtin_amdgcn_mfma_scale_f32_32x32x64_f8f6f4(
        fa0, fb0, acc[0][0], 0, 0, 0, 127, 0, 127);
    acc[0][1] = __builtin_amdgcn_mfma_scale_f32_32x32x64_f8f6f4(
        fa0, fb1, acc[0][1], 0, 0, 0, 127, 0, 127);
    acc[1][0] = __builtin_amdgcn_mfma_scale_f32_32x32x64_f8f6f4(
        fa1, fb0, acc[1][0], 0, 0, 0, 127, 0, 127);
    acc[1][1] = __builtin_amdgcn_mfma_scale_f32_32x32x64_f8f6f4(
        fa1, fb1, acc[1][1], 0, 0, 0, 127, 0, 127);
    __builtin_amdgcn_s_setprio(0);
    __builtin_amdgcn_sched_barrier(0);
    // ---- cluster 3: k-step 1 fragment loads (reuse the same 32 VGPR) ----
    fa0 = *(const i32x8*)(bufa + (aOff[0] ^ 64u));
    fa1 = *(const i32x8*)(bufa + (aOff[1] ^ 64u));
    fb0 = *(const i32x8*)(bufb + (bOff[0] ^ 64u));
    fb1 = *(const i32x8*)(bufb + (bOff[1] ^ 64u));
    __builtin_amdgcn_sched_barrier(0);
    // ---- cluster 4: k-step 1 MFMA ----
    __builtin_amdgcn_s_setprio(1);
    acc[0][0] = __builtin_amdgcn_mfma_scale_f32_32x32x64_f8f6f4(
        fa0, fb0, acc[0][0], 0, 0, 0, 127, 0, 127);
    acc[0][1] = __builtin_amdgcn_mfma_scale_f32_32x32x64_f8f6f4(
        fa0, fb1, acc[0][1], 0, 0, 0, 127, 0, 127);
    acc[1][0] = __builtin_amdgcn_mfma_scale_f32_32x32x64_f8f6f4(
        fa1, fb0, acc[1][0], 0, 0, 0, 127, 0, 127);
    acc[1][1] = __builtin_amdgcn_mfma_scale_f32_32x32x64_f8f6f4(
        fa1, fb1, acc[1][1], 0, 0, 0, 127, 0, 127);
    __builtin_amdgcn_s_setprio(0);
    __builtin_amdgcn_sched_barrier(0);
    // This tile's reads done (lgkm), next tile's stage landed (vm) -> barrier.
    asm volatile("s_waitcnt lgkmcnt(0)" ::: "memory");
    asm volatile("s_waitcnt vmcnt(0)" ::: "memory");
    __builtin_amdgcn_sched_barrier(0);
    __builtin_amdgcn_s_barrier();
  }

  // ---- epilogue: logits in-place, diag, fused online-LSE partials ----
  // 32x32 C/D layout (m74/m101, dtype-independent):
  //   col = lane&31, row = (reg&3) + 8*(reg>>2) + 4*(lane>>5).
  float temp = fminf(expf(log_temp[0]), 100.0f);
#pragma unroll
  for (int mi = 0; mi < 2; ++mi) {
#pragma unroll
    for (int reg = 0; reg < 16; ++reg) {
      int rl = wr * 64 + mi * 32 + (reg & 3) + 8 * (reg >> 2) + 4 * kh;
      float asq = a_sq[brow + rl];
#pragma unroll
      for (int ni = 0; ni < 2; ++ni) {
        float bsq = b_sq[bcol + wc * 64 + ni * 32 + l31];
        acc[mi][ni][reg] = -temp * (asq + bsq - 2.0f * acc[mi][ni][reg]);
      }
    }
  }
  // Diagonal: block contains global diag iff (bm>>1)==bn.
  if ((bm >> 1) == bn) {
#pragma unroll
    for (int mi = 0; mi < 2; ++mi)
#pragma unroll
      for (int ni = 0; ni < 2; ++ni)
#pragma unroll
        for (int reg = 0; reg < 16; ++reg) {
          int rl = wr * 64 + mi * 32 + (reg & 3) + 8 * (reg >> 2) + 4 * kh;
          int cl = wc * 64 + ni * 32 + l31;
          if (brow + rl == bcol + cl) diag[brow + rl] = acc[mi][ni][reg];
        }
  }
  // Row partials: per (mi,reg): 2 in-lane + reduce across 32 cols (l31).
#pragma unroll
  for (int mi = 0; mi < 2; ++mi) {
#pragma unroll
    for (int reg = 0; reg < 16; ++reg) {
      float mx = fmaxf(acc[mi][0][reg], acc[mi][1][reg]);
#pragma unroll
      for (int o = 1; o < 32; o <<= 1) mx = fmaxf(mx, __shfl_xor(mx, o));
      float s = __expf(acc[mi][0][reg] - mx) + __expf(acc[mi][1][reg] - mx);
#pragma unroll
      for (int o = 1; o < 32; o <<= 1) s += __shfl_xor(s, o);
      if (l31 == 0) {
        int row = brow + wr * 64 + mi * 32 + (reg & 3) + 8 * (reg >> 2) + 4 * kh;
        int ch = bn * 4 + wc;
        rowM[(size_t)row * 64 + ch] = mx;
        rowS[(size_t)row * 64 + ch] = s;
      }
    }
  }
  // Col partials: per ni: 32 in-lane (mi,reg) + merge kh halves (xor 32).
#pragma unroll
  for (int ni = 0; ni < 2; ++ni) {
    float mx = -INFINITY;
#pragma unroll
    for (int mi = 0; mi < 2; ++mi)
#pragma unroll
      for (int reg = 0; reg < 16; ++reg) mx = fmaxf(mx, acc[mi][ni][reg]);
    mx = fmaxf(mx, __shfl_xor(mx, 32));
    float s = 0.f;
#pragma unroll
    for (int mi = 0; mi < 2; ++mi)
#pragma unroll
      for (int reg = 0; reg < 16; ++reg) s += __expf(acc[mi][ni][reg] - mx);
    s += __shfl_xor(s, 32);
    if (kh == 0) {
      int col = bcol + wc * 64 + ni * 32 + l31;
      int ch = bm * 2 + wr;
      colM[(size_t)col * 64 + ch] = mx;
      colS[(size_t)col * 64 + ch] = s;
    }
  }
}

// ---------------------------------------------------------------------------
// Kernel 3: combine 64 chunk-partials per row/col -> (lse - diag).
// ---------------------------------------------------------------------------
__global__ __launch_bounds__(256) void combine_kernel(
    const float* __restrict__ rowM, const float* __restrict__ rowS,
    const float* __restrict__ colM, const float* __restrict__ colS,
    const float* __restrict__ diag, float* __restrict__ hrow,
    float* __restrict__ hcol) {
  int b = blockIdx.x;
  int t = threadIdx.x;
  int wave = t >> 6, lane = t & 63;
  int isCol = b >> 10;
  int idx = (b & 1023) * 4 + wave;
  const float* PM = isCol ? colM : rowM;
  const float* PS = isCol ? colS : rowS;
  float M = PM[(size_t)idx * 64 + lane];
  float S = PS[(size_t)idx * 64 + lane];
#pragma unroll
  for (int o = 1; o < 64; o <<= 1) {
    float M2 = __shfl_xor(M, o), S2 = __shfl_xor(S, o);
    float nM = fmaxf(M, M2);
    S = S * __expf(M - nM) + S2 * __expf(M2 - nM);
    M = nM;
  }
  if (lane == 0) {
    float v = M + logf(S) - diag[idx];
    (isCol ? hcol : hrow)[idx] = v;
  }
}

// Kernel 4: final mean in f64: 0.5*(mean(hrow) + mean(hcol)).
__global__ __launch_bounds__(256) void final_kernel(
    const float* __restrict__ hrow, const float* __restrict__ hcol,
    float* __restrict__ out) {
  int t = threadIdx.x;
  double a = 0.0;
  for (int i = t; i < NB; i += 256) {
    a += 0.5 * ((double)hrow[i] + (double)hcol[i]);
  }
#pragma unroll
  for (int o = 32; o > 0; o >>= 1) a += __shfl_xor(a, o);
  __shared__ double sd[4];
  if ((t & 63) == 0) sd[t >> 6] = a;
  __syncthreads();
  if (t == 0) out[0] = (float)(((sd[0] + sd[1]) + (sd[2] + sd[3])) / (double)NB);
}

extern "C" void kernel_launch(void* const* d_in, const int* in_sizes, int n_in,
                              void* d_out, int out_size, void* d_ws, size_t ws_size,
                              hipStream_t stream) {
  const float* v_mean = (const float*)d_in[0];
  const float* v_var = (const float*)d_in[1];
  const float* t_mean = (const float*)d_in[2];
  const float* t_var = (const float*)d_in[3];
  const float* log_temp = (const float*)d_in[4];
  float* out = (float*)d_out;

  char* ws = (char*)d_ws;
  unsigned char* Afp = (unsigned char*)ws;                       // 4 MiB
  unsigned char* Bfp = (unsigned char*)(ws + 4194304);           // 4 MiB
  float* rowM = (float*)(ws + 8388608);                          // 1 MiB each
  float* rowS = rowM + (size_t)NB * 64;
  float* colM = rowS + (size_t)NB * 64;
  float* colS = colM + (size_t)NB * 64;
  float* diag = colS + (size_t)NB * 64;                          // 16 KiB each
  float* hrow = diag + NB;
  float* hcol = hrow + NB;
  float* a_sq = hcol + NB;
  float* b_sq = a_sq + NB;

  prep_kernel<<<8192, 256, 0, stream>>>(v_mean, v_var, t_mean, t_var, Afp, Bfp, a_sq, b_sq);
  gemm_fused_kernel<<<512, 512, 0, stream>>>(Afp, Bfp, a_sq, b_sq, log_temp,
                                             rowM, rowS, colM, colS, diag);
  combine_kernel<<<2048, 256, 0, stream>>>(rowM, rowS, colM, colS, diag, hrow, hcol);
  final_kernel<<<1, 256, 0, stream>>>(hrow, hcol, out);
}

// Round 10
// 64.436 us; speedup vs baseline: 1.6318x; 1.6318x over previous
//
#include <hip/hip_runtime.h>
#include <math.h>

#define NB 4096
#define ND 512
#define K2 1024
#define NT8 8  // K2 / 128 K-tiles

typedef __attribute__((ext_vector_type(4))) float f32x4;
typedef __attribute__((ext_vector_type(16))) float f32x16;

__device__ __forceinline__ float wave_sum(float v) {
#pragma unroll
  for (int o = 32; o > 0; o >>= 1) v += __shfl_xor(v, o);
  return v;
}

// ---------------------------------------------------------------------------
// Kernel 1: build A=[v_mean|v_sigma], B=[t_mean|t_sigma] in fp8 e4m3
// (4096x1024, 1 B/elem), plus exact f32 row square-norms
// a_sq[i] = Σ mean² + Σ var (σ²=var). Blocks 0..4095 A-side, 4096..8191 B.
// ---------------------------------------------------------------------------
__global__ __launch_bounds__(256) void prep_kernel(
    const float* __restrict__ v_mean, const float* __restrict__ v_var,
    const float* __restrict__ t_mean, const float* __restrict__ t_var,
    unsigned char* __restrict__ Afp, unsigned char* __restrict__ Bfp,
    float* __restrict__ a_sq, float* __restrict__ b_sq) {
  int b = blockIdx.x;
  int side = b >> 12;
  int row = b & (NB - 1);
  const float* mean = side ? t_mean : v_mean;
  const float* var = side ? t_var : v_var;
  unsigned char* dst = side ? Bfp : Afp;
  float* sq = side ? b_sq : a_sq;
  int t = threadIdx.x;
  float2 m2 = *(const float2*)(mean + (size_t)row * ND + 2 * t);
  float2 v2 = *(const float2*)(var + (size_t)row * ND + 2 * t);
  float s0 = sqrtf(v2.x), s1 = sqrtf(v2.y);
  int pm = __builtin_amdgcn_cvt_pk_fp8_f32(m2.x, m2.y, 0, false);
  int ps = __builtin_amdgcn_cvt_pk_fp8_f32(s0, s1, 0, false);
  *(unsigned short*)(dst + (size_t)row * K2 + 2 * t) = (unsigned short)(pm & 0xFFFF);
  *(unsigned short*)(dst + (size_t)row * K2 + ND + 2 * t) = (unsigned short)(ps & 0xFFFF);
  float p = m2.x * m2.x + m2.y * m2.y + v2.x + v2.y;
  p = wave_sum(p);
  __shared__ float sm[4];
  if ((t & 63) == 0) sm[t >> 6] = p;
  __syncthreads();
  if (t == 0) sq[row] = (sm[0] + sm[1]) + (sm[2] + sm[3]);
}

// ---------------------------------------------------------------------------
// Kernel 2: 128x256-tile fp8 GEMM via NON-SCALED mfma_f32_32x32x16_fp8_fp8
// (full rate = 2190 TF, m35). Operands are 2 VGPRs (one b64 LDS read), so
// per-kstep fragment liveness is 8 regs — the register-pressure fix after
// the scale-MFMA (i32x8 operand) path spilled in R7/R8/R9.
// BK=128 staged (8 ksteps of K=16), SINGLE-buffered LDS (48 KiB) -> 2
// blocks/CU co-reside (R5's proven TLP structure). __launch_bounds__(512,4).
// 8 waves (2Mx4N), wave = 64x64 = 2x2 of 32x32, acc = 2x2xf32x16 (64 regs).
//
// LDS: 128B rows, 16B-granule swizzle phys = logical ^ ((row&7)<<4), staged
// with inverse-swizzled global source (rule #21) — R5's verified geometry.
// b64 frag reads: 4 distinct addrs/bank over the min 4 phases -> conflict-free.
// Fused online-LSE partials in the epilogue:
//   rowM/rowS[row][64]  ch = bn*4+wc    colM/colS[col][64]  ch = bm*2+wr
// ---------------------------------------------------------------------------
__global__ __launch_bounds__(512, 4) void gemm_fused_kernel(
    const unsigned char* __restrict__ Afp, const unsigned char* __restrict__ Bfp,
    const float* __restrict__ a_sq, const float* __restrict__ b_sq,
    const float* __restrict__ log_temp,
    float* __restrict__ rowM, float* __restrict__ rowS,
    float* __restrict__ colM, float* __restrict__ colS,
    float* __restrict__ diag) {
  __shared__ unsigned char ldsA[128 * 128];  // 16 KB
  __shared__ unsigned char ldsB[256 * 128];  // 32 KB
  int bid = blockIdx.x;
  // XCD-aware swizzle: 512 blocks, 8 XCDs -> 64 contiguous per XCD (bijective).
  int swz = (bid & 7) * 64 + (bid >> 3);
  int bm = swz >> 4, bn = swz & 15;  // 32 x 16 grid
  int brow = bm * 128, bcol = bn * 256;
  int tid = threadIdx.x;
  int lane = tid & 63, wid = tid >> 6;
  int wr = wid >> 2, wc = wid & 3;  // 2x4 wave grid, wave = 64x64
  int l31 = lane & 31, kh = lane >> 5;

  // Staging offsets (6 x 16B loads/thread): inverse-swizzled global byte
  // offsets + linear LDS byte offsets (R5/R8 geometry, verified).
  int rbase = tid >> 3, chunk = tid & 7;
  unsigned gA[2], gB[4];
  int ldA[2], ldB[4];
#pragma unroll
  for (int s = 0; s < 2; ++s) {
    int row = s * 64 + rbase;
    gA[s] = (unsigned)(brow + row) * K2 + ((chunk * 16) ^ ((row & 7) << 4));
    ldA[s] = row * 128 + chunk * 16;
  }
#pragma unroll
  for (int s = 0; s < 4; ++s) {
    int row = s * 64 + rbase;
    gB[s] = (unsigned)(bcol + row) * K2 + ((chunk * 16) ^ ((row & 7) << 4));
    ldB[s] = row * 128 + chunk * 16;
  }

#define STAGE(T)                                                               \
  {                                                                            \
    _Pragma("unroll") for (int s = 0; s < 2; ++s)                              \
        __builtin_amdgcn_global_load_lds(                                      \
            (const __attribute__((address_space(1))) unsigned int*)(Afp +      \
                gA[s] + (unsigned)(T) * 128),                                  \
            (__attribute__((address_space(3))) unsigned int*)(ldsA + ldA[s]),  \
            16, 0, 0);                                                         \
    _Pragma("unroll") for (int s = 0; s < 4; ++s)                              \
        __builtin_amdgcn_global_load_lds(                                      \
            (const __attribute__((address_space(1))) unsigned int*)(Bfp +      \
                gB[s] + (unsigned)(T) * 128),                                  \
            (__attribute__((address_space(3))) unsigned int*)(ldsB + ldB[s]),  \
            16, 0, 0);                                                         \
  }

  // Fragment bases: 32x32x16 fp8 A/B layout: row(col) = lane&31,
  // k = (lane>>5)*8 + j, j=0..7 packed in one b64.
  // Byte addr(ks) = base + (((ks<<4) ^ sw)), sw = (row&7)<<4 = (lane&7)<<4;
  // (ks*16 | kh*8 have disjoint bits, so the XOR decomposes.)
  unsigned sw = (unsigned)(lane & 7) << 4;
  unsigned aB[2], bB[2];
#pragma unroll
  for (int mi = 0; mi < 2; ++mi)
    aB[mi] = (unsigned)(wr * 64 + mi * 32 + l31) * 128 + (unsigned)kh * 8;
#pragma unroll
  for (int ni = 0; ni < 2; ++ni)
    bB[ni] = (unsigned)(wc * 64 + ni * 32 + l31) * 128 + (unsigned)kh * 8;

  f32x16 acc[2][2] = {};

  STAGE(0);
  asm volatile("s_waitcnt vmcnt(0)" ::: "memory");
  __builtin_amdgcn_s_barrier();

  for (int t = 0; t < NT8; ++t) {
    long a0, a1, b0, b1;
    // ksteps 0..6: read 4 x b64 (8 regs) + 4 MFMA each.
#pragma unroll
    for (int ks = 0; ks < 7; ++ks) {
      unsigned ko = ((unsigned)ks << 4) ^ sw;
      a0 = *(const long*)(ldsA + aB[0] + ko);
      a1 = *(const long*)(ldsA + aB[1] + ko);
      b0 = *(const long*)(ldsB + bB[0] + ko);
      b1 = *(const long*)(ldsB + bB[1] + ko);
      __builtin_amdgcn_s_setprio(1);
      acc[0][0] = __builtin_amdgcn_mfma_f32_32x32x16_fp8_fp8(a0, b0, acc[0][0], 0, 0, 0);
      acc[0][1] = __builtin_amdgcn_mfma_f32_32x32x16_fp8_fp8(a0, b1, acc[0][1], 0, 0, 0);
      acc[1][0] = __builtin_amdgcn_mfma_f32_32x32x16_fp8_fp8(a1, b0, acc[1][0], 0, 0, 0);
      acc[1][1] = __builtin_amdgcn_mfma_f32_32x32x16_fp8_fp8(a1, b1, acc[1][1], 0, 0, 0);
      __builtin_amdgcn_s_setprio(0);
    }
    // kstep 7: read, drain LDS reads, barrier -> tile fully consumed.
    unsigned ko7 = (7u << 4) ^ sw;
    a0 = *(const long*)(ldsA + aB[0] + ko7);
    a1 = *(const long*)(ldsA + aB[1] + ko7);
    b0 = *(const long*)(ldsB + bB[0] + ko7);
    b1 = *(const long*)(ldsB + bB[1] + ko7);
    asm volatile("s_waitcnt lgkmcnt(0)" ::: "memory");
    __builtin_amdgcn_s_barrier();
    // Restage same buffer for tile t+1 (async; lands before next barrier).
    if (t + 1 < NT8) STAGE(t + 1);
    // kstep 7 MFMA on registers, overlapping the stage flight time.
    __builtin_amdgcn_s_setprio(1);
    acc[0][0] = __builtin_amdgcn_mfma_f32_32x32x16_fp8_fp8(a0, b0, acc[0][0], 0, 0, 0);
    acc[0][1] = __builtin_amdgcn_mfma_f32_32x32x16_fp8_fp8(a0, b1, acc[0][1], 0, 0, 0);
    acc[1][0] = __builtin_amdgcn_mfma_f32_32x32x16_fp8_fp8(a1, b0, acc[1][0], 0, 0, 0);
    acc[1][1] = __builtin_amdgcn_mfma_f32_32x32x16_fp8_fp8(a1, b1, acc[1][1], 0, 0, 0);
    __builtin_amdgcn_s_setprio(0);
    asm volatile("s_waitcnt vmcnt(0)" ::: "memory");
    __builtin_amdgcn_s_barrier();
  }

  // ---- epilogue: logits in-place, diag, fused online-LSE partials ----
  // 32x32 C/D layout (m74/m101, dtype-independent):
  //   col = lane&31, row = (reg&3) + 8*(reg>>2) + 4*(lane>>5).
  float temp = fminf(expf(log_temp[0]), 100.0f);
#pragma unroll
  for (int mi = 0; mi < 2; ++mi) {
#pragma unroll
    for (int reg = 0; reg < 16; ++reg) {
      int rl = wr * 64 + mi * 32 + (reg & 3) + 8 * (reg >> 2) + 4 * kh;
      float asq = a_sq[brow + rl];
#pragma unroll
      for (int ni = 0; ni < 2; ++ni) {
        float bsq = b_sq[bcol + wc * 64 + ni * 32 + l31];
        acc[mi][ni][reg] = -temp * (asq + bsq - 2.0f * acc[mi][ni][reg]);
      }
    }
  }
  // Diagonal: block contains global diag iff (bm>>1)==bn.
  if ((bm >> 1) == bn) {
#pragma unroll
    for (int mi = 0; mi < 2; ++mi)
#pragma unroll
      for (int ni = 0; ni < 2; ++ni)
#pragma unroll
        for (int reg = 0; reg < 16; ++reg) {
          int rl = wr * 64 + mi * 32 + (reg & 3) + 8 * (reg >> 2) + 4 * kh;
          int cl = wc * 64 + ni * 32 + l31;
          if (brow + rl == bcol + cl) diag[brow + rl] = acc[mi][ni][reg];
        }
  }
  // Row partials: per (mi,reg): 2 in-lane + reduce across 32 cols (l31).
#pragma unroll
  for (int mi = 0; mi < 2; ++mi) {
#pragma unroll
    for (int reg = 0; reg < 16; ++reg) {
      float mx = fmaxf(acc[mi][0][reg], acc[mi][1][reg]);
#pragma unroll
      for (int o = 1; o < 32; o <<= 1) mx = fmaxf(mx, __shfl_xor(mx, o));
      float s = __expf(acc[mi][0][reg] - mx) + __expf(acc[mi][1][reg] - mx);
#pragma unroll
      for (int o = 1; o < 32; o <<= 1) s += __shfl_xor(s, o);
      if (l31 == 0) {
        int row = brow + wr * 64 + mi * 32 + (reg & 3) + 8 * (reg >> 2) + 4 * kh;
        int ch = bn * 4 + wc;
        rowM[(size_t)row * 64 + ch] = mx;
        rowS[(size_t)row * 64 + ch] = s;
      }
    }
  }
  // Col partials: per ni: 32 in-lane (mi,reg) + merge kh halves (xor 32).
#pragma unroll
  for (int ni = 0; ni < 2; ++ni) {
    float mx = -INFINITY;
#pragma unroll
    for (int mi = 0; mi < 2; ++mi)
#pragma unroll
      for (int reg = 0; reg < 16; ++reg) mx = fmaxf(mx, acc[mi][ni][reg]);
    mx = fmaxf(mx, __shfl_xor(mx, 32));
    float s = 0.f;
#pragma unroll
    for (int mi = 0; mi < 2; ++mi)
#pragma unroll
      for (int reg = 0; reg < 16; ++reg) s += __expf(acc[mi][ni][reg] - mx);
    s += __shfl_xor(s, 32);
    if (kh == 0) {
      int col = bcol + wc * 64 + ni * 32 + l31;
      int ch = bm * 2 + wr;
      colM[(size_t)col * 64 + ch] = mx;
      colS[(size_t)col * 64 + ch] = s;
    }
  }
}

// ---------------------------------------------------------------------------
// Kernel 3: combine 64 chunk-partials per row/col -> (lse - diag).
// ---------------------------------------------------------------------------
__global__ __launch_bounds__(256) void combine_kernel(
    const float* __restrict__ rowM, const float* __restrict__ rowS,
    const float* __restrict__ colM, const float* __restrict__ colS,
    const float* __restrict__ diag, float* __restrict__ hrow,
    float* __restrict__ hcol) {
  int b = blockIdx.x;
  int t = threadIdx.x;
  int wave = t >> 6, lane = t & 63;
  int isCol = b >> 10;
  int idx = (b & 1023) * 4 + wave;
  const float* PM = isCol ? colM : rowM;
  const float* PS = isCol ? colS : rowS;
  float M = PM[(size_t)idx * 64 + lane];
  float S = PS[(size_t)idx * 64 + lane];
#pragma unroll
  for (int o = 1; o < 64; o <<= 1) {
    float M2 = __shfl_xor(M, o), S2 = __shfl_xor(S, o);
    float nM = fmaxf(M, M2);
    S = S * __expf(M - nM) + S2 * __expf(M2 - nM);
    M = nM;
  }
  if (lane == 0) {
    float v = M + logf(S) - diag[idx];
    (isCol ? hcol : hrow)[idx] = v;
  }
}

// Kernel 4: final mean in f64: 0.5*(mean(hrow) + mean(hcol)).
__global__ __launch_bounds__(256) void final_kernel(
    const float* __restrict__ hrow, const float* __restrict__ hcol,
    float* __restrict__ out) {
  int t = threadIdx.x;
  double a = 0.0;
  for (int i = t; i < NB; i += 256) {
    a += 0.5 * ((double)hrow[i] + (double)hcol[i]);
  }
#pragma unroll
  for (int o = 32; o > 0; o >>= 1) a += __shfl_xor(a, o);
  __shared__ double sd[4];
  if ((t & 63) == 0) sd[t >> 6] = a;
  __syncthreads();
  if (t == 0) out[0] = (float)(((sd[0] + sd[1]) + (sd[2] + sd[3])) / (double)NB);
}

extern "C" void kernel_launch(void* const* d_in, const int* in_sizes, int n_in,
                              void* d_out, int out_size, void* d_ws, size_t ws_size,
                              hipStream_t stream) {
  const float* v_mean = (const float*)d_in[0];
  const float* v_var = (const float*)d_in[1];
  const float* t_mean = (const float*)d_in[2];
  const float* t_var = (const float*)d_in[3];
  const float* log_temp = (const float*)d_in[4];
  float* out = (float*)d_out;

  char* ws = (char*)d_ws;
  unsigned char* Afp = (unsigned char*)ws;                       // 4 MiB
  unsigned char* Bfp = (unsigned char*)(ws + 4194304);           // 4 MiB
  float* rowM = (float*)(ws + 8388608);                          // 1 MiB each
  float* rowS = rowM + (size_t)NB * 64;
  float* colM = rowS + (size_t)NB * 64;
  float* colS = colM + (size_t)NB * 64;
  float* diag = colS + (size_t)NB * 64;                          // 16 KiB each
  float* hrow = diag + NB;
  float* hcol = hrow + NB;
  float* a_sq = hcol + NB;
  float* b_sq = a_sq + NB;

  prep_kernel<<<8192, 256, 0, stream>>>(v_mean, v_var, t_mean, t_var, Afp, Bfp, a_sq, b_sq);
  gemm_fused_kernel<<<512, 512, 0, stream>>>(Afp, Bfp, a_sq, b_sq, log_temp,
                                             rowM, rowS, colM, colS, diag);
  combine_kernel<<<2048, 256, 0, stream>>>(rowM, rowS, colM, colS, diag, hrow, hcol);
  final_kernel<<<1, 256, 0, stream>>>(hrow, hcol, out);
}